// Round 7
// baseline (137.911 us; speedup 1.0000x reference)
//
#include <hip/hip_runtime.h>
#include <math.h>

#define BB 8
#define LL 1024
#define HH 8
#define DD 64
#define SS 35
#define UU 35
#define BH (BB*HH)
#define CH 32            // cumsum chunks per (b,h)
#define CROWS (LL/CH)    // 32 rows per chunk
#define NCHK 4           // attention K/V chunks
#define CHK 256          // keys per chunk
#define RPAD 48          // padded row count (35 -> 48, 3 m-tiles)

#define MBLOCKS 16384    // stage-1: 4 q per 256-thread block (wave per q)
#define C1BLOCKS (BH*CH) // 2048

typedef __attribute__((ext_vector_type(8))) short short8;
typedef __attribute__((ext_vector_type(4))) float f32x4;

__device__ __forceinline__ size_t qkv_off(int b, int l, int h, int d) {
    return (((size_t)b*LL + l)*HH + h)*DD + d;
}

__device__ __forceinline__ unsigned short f2bf(float x) {
    unsigned int u = __float_as_uint(x);
    u = (u + 0x7fffu + ((u >> 16) & 1u)) >> 16;
    return (unsigned short)u;
}

__device__ __forceinline__ short8 ld_bf8_g(const float* __restrict__ p) {
    float4 x = *reinterpret_cast<const float4*>(p);
    float4 y = *reinterpret_cast<const float4*>(p + 4);
    short8 r;
    r[0] = (short)f2bf(x.x); r[1] = (short)f2bf(x.y);
    r[2] = (short)f2bf(x.z); r[3] = (short)f2bf(x.w);
    r[4] = (short)f2bf(y.x); r[5] = (short)f2bf(y.y);
    r[6] = (short)f2bf(y.z); r[7] = (short)f2bf(y.w);
    return r;
}

// ---------------- L1: kernel_M (wave/q, lane/sample) + csum1 fused ----------------
__global__ __launch_bounds__(256, 5) void kernel_M_csum1(const float* __restrict__ Q,
                                                         const float* __restrict__ K,
                                                         const float* __restrict__ V,
                                                         const int*   __restrict__ sidx,
                                                         float* __restrict__ M,
                                                         float* __restrict__ csum) {
    int blk = blockIdx.x;
    if (blk < MBLOCKS) {
        // ---- sparsity measurement M: one WAVE per q, one LANE per sample ----
        __shared__ float qs[256];            // 4 q-rows of 64 floats
        int xcd  = blk & 7;
        int slot = blk >> 3;                 // 0..2047
        int bh   = ((slot >> 8) << 3) | xcd; // bh%8 == xcd -> per-XCD K locality in L2
        int j    = slot & 255;
        int tid  = threadIdx.x;
        int widx = tid >> 6, lane = tid & 63;
        int q    = j * 4 + widx;
        int b = bh >> 3, h = bh & 7;
        int base = (b << 19) + (h << 6);     // elem offset of (b, 0, h, 0); l-stride = 512

        // stage this block's 4 q-rows into LDS (coalesced; broadcast-read later)
        qs[tid] = Q[(size_t)base + (size_t)q * 512 + lane];
        __syncthreads();

        float dot = 0.f;
        if (lane < SS) {
            int idx = sidx[q * SS + lane];               // one coalesced 140B load
            const f32x4* kr = reinterpret_cast<const f32x4*>(K + base + (size_t)idx * 512);
            // 16 independent 16B gathers: full K row in flight per lane
            f32x4 kb[16];
#pragma unroll
            for (int i = 0; i < 16; i++) kb[i] = kr[i];
            const f32x4* qp = reinterpret_cast<const f32x4*>(qs + widx * 64);
            float d0 = 0.f, d1 = 0.f, d2 = 0.f, d3 = 0.f;
#pragma unroll
            for (int i = 0; i < 16; i++) {
                f32x4 qq = qp[i];                        // uniform addr -> LDS broadcast
                d0 += qq.x * kb[i].x;
                d1 += qq.y * kb[i].y;
                d2 += qq.z * kb[i].z;
                d3 += qq.w * kb[i].w;
            }
            dot = (d0 + d1) + (d2 + d3);
        }
        float mx = (lane < SS) ? dot : -INFINITY;
        float sm = (lane < SS) ? dot : 0.f;
#pragma unroll
        for (int x = 1; x < 64; x <<= 1) {
            mx = fmaxf(mx, __shfl_xor(mx, x));
            sm += __shfl_xor(sm, x);
        }
        if (lane == 0) M[bh * LL + q] = mx - sm * (1.0f / LL);
    } else {
        // ---- csum1: per-chunk column sums ----
        int blk2 = blk - MBLOCKS;
        int bh = blk2 >> 5, c = blk2 & (CH - 1);
        int b = bh >> 3, h = bh & 7;
        int d = threadIdx.x & 63, seg = threadIdx.x >> 6;
        int l0 = c * CROWS + seg * (CROWS / 4);
        const float* vp = V + qkv_off(b, l0, h, d);
        float vr[CROWS / 4];
#pragma unroll
        for (int i = 0; i < CROWS / 4; i++) vr[i] = vp[(size_t)i * (HH * DD)];
        float s = 0.f;
#pragma unroll
        for (int i = 0; i < CROWS / 4; i++) s += vr[i];
        __shared__ float red[4][64];
        red[seg][d] = s;
        __syncthreads();
        if (seg == 0)
            csum[(size_t)blk2 * 64 + d] = red[0][d] + red[1][d] + red[2][d] + red[3][d];
    }
}

// ---------------- L2: topk + csum2 fused (64-thread blocks) ----------------
__global__ __launch_bounds__(64, 4) void kernel_topk_csum2(const float* __restrict__ M,
                                                           int* __restrict__ top,
                                                           const float* __restrict__ V,
                                                           const float* __restrict__ csum,
                                                           float* __restrict__ out) {
    if (blockIdx.x < BH) {
        // ---- top-U per (b,h), single wave, shfl-only ----
        int bh = blockIdx.x, lane = threadIdx.x;
        float v[16];
#pragma unroll
        for (int i = 0; i < 16; i++) v[i] = M[bh * LL + i * 64 + lane];

        for (int k = 0; k < UU; k++) {
            float bv = -INFINITY; int bi = 0x7fffffff;
#pragma unroll
            for (int i = 0; i < 16; i++) {
                if (v[i] > bv) { bv = v[i]; bi = i * 64 + lane; }
            }
#pragma unroll
            for (int w = 1; w < 64; w <<= 1) {
                float ov = __shfl_xor(bv, w);
                int   oi = __shfl_xor(bi, w);
                if (ov > bv || (ov == bv && oi < bi)) { bv = ov; bi = oi; }
            }
            if (lane == 0) top[bh * UU + k] = bi;
            if ((bi & 63) == lane) {
                int slot = bi >> 6;
#pragma unroll
                for (int i = 0; i < 16; i++) if (i == slot) v[i] = -INFINITY;
            }
        }
    } else {
        // ---- csum2: scan within chunk, write context ----
        int blk = blockIdx.x - BH;
        int bh = blk >> 5, c = blk & (CH - 1);
        int b = bh >> 3, h = bh & 7;
        int d = threadIdx.x;
        int l0 = c * CROWS;
        const float* vp = V + qkv_off(b, l0, h, d);

        float vr[CROWS];
#pragma unroll
        for (int i = 0; i < CROWS; i++) vr[i] = vp[(size_t)i * (HH * DD)];

        float prefix = 0.f;
#pragma unroll
        for (int cc = 0; cc < CH; cc++) {
            float vv = csum[(size_t)(bh * CH + cc) * 64 + d];
            prefix += (cc < c) ? vv : 0.f;
        }
        float* op = out + qkv_off(b, l0, h, d);
        float run = prefix;
#pragma unroll
        for (int i = 0; i < CROWS; i++) {
            run += vr[i];
            op[(size_t)i * (HH * DD)] = run / (float)(l0 + i + 1);
        }
    }
}

// ---------------- Stage 4a: MFMA flash-attention partials per (bh, chunk) ----------------
__global__ __launch_bounds__(256) void kernel_attn_part(const float* __restrict__ Q,
                                                        const float* __restrict__ K,
                                                        const float* __restrict__ V,
                                                        const int*   __restrict__ top,
                                                        float* __restrict__ m_ws,
                                                        float* __restrict__ se_ws,
                                                        float* __restrict__ pv_ws) {
    __shared__ unsigned short vt[64 * CHK];      // V^T, 16B-slot swizzled
    __shared__ unsigned short p_lds[RPAD * CHK]; // P (exp'd scores), bf16
    __shared__ float red_m[4][RPAD];
    __shared__ float red_se[4][RPAD];
    __shared__ int   qpos_s[RPAD];

    const int blk = blockIdx.x;          // bh*NCHK + ch
    const int bh  = blk >> 2;
    const int ch  = blk & 3;
    const int b   = bh >> 3, h = bh & 7;
    const int l0  = ch * CHK;
    const int tid = threadIdx.x;
    const int w    = tid >> 6;
    const int lane = tid & 63;
    const int c    = lane & 15;
    const int g    = lane >> 4;
    const float scale = 0.125f;

    if (tid < RPAD) qpos_s[tid] = top[bh * UU + (tid < UU ? tid : UU - 1)];

#pragma unroll
    for (int i = 0; i < 8; i++) {
        int task = i * 256 + tid;
        int d   = task & 63;
        int lq8 = task >> 6;
        float vv[8];
#pragma unroll
        for (int j = 0; j < 8; j++)
            vv[j] = V[qkv_off(b, l0 + lq8 * 8 + j, h, d)];
        short8 pk;
#pragma unroll
        for (int j = 0; j < 8; j++) pk[j] = (short)f2bf(vv[j]);
        *reinterpret_cast<short8*>(vt + d * CHK + (((lq8 ^ (d & 31)) << 3))) = pk;
    }
    __syncthreads();

    f32x4 acc[3][4];
#pragma unroll
    for (int mt = 0; mt < 3; mt++)
#pragma unroll
        for (int nt = 0; nt < 4; nt++) acc[mt][nt] = (f32x4){0.f, 0.f, 0.f, 0.f};

#pragma unroll
    for (int ks = 0; ks < 2; ks++) {
        int k0 = ks * 32 + g * 8;
        short8 af[3];
#pragma unroll
        for (int mt = 0; mt < 3; mt++) {
            int row = mt * 16 + c;
            af[mt] = ld_bf8_g(Q + qkv_off(b, qpos_s[row], h, k0));
        }
#pragma unroll
        for (int nt = 0; nt < 4; nt++) {
            int kl = l0 + w * 64 + nt * 16 + c;
            short8 bf = ld_bf8_g(K + qkv_off(b, kl, h, k0));
#pragma unroll
            for (int mt = 0; mt < 3; mt++)
                acc[mt][nt] = __builtin_amdgcn_mfma_f32_16x16x32_bf16(af[mt], bf, acc[mt][nt], 0, 0, 0);
        }
    }

    float tmax[3][4];
#pragma unroll
    for (int mt = 0; mt < 3; mt++)
#pragma unroll
        for (int r = 0; r < 4; r++) {
            float m = fmaxf(fmaxf(acc[mt][0][r], acc[mt][1][r]),
                            fmaxf(acc[mt][2][r], acc[mt][3][r]));
            m = fmaxf(m, __shfl_xor(m, 1));
            m = fmaxf(m, __shfl_xor(m, 2));
            m = fmaxf(m, __shfl_xor(m, 4));
            m = fmaxf(m, __shfl_xor(m, 8));
            tmax[mt][r] = m;
        }
    if (c == 0) {
#pragma unroll
        for (int mt = 0; mt < 3; mt++)
#pragma unroll
            for (int r = 0; r < 4; r++)
                red_m[w][mt * 16 + g * 4 + r] = tmax[mt][r];
    }
    __syncthreads();

    float tse[3][4];
#pragma unroll
    for (int mt = 0; mt < 3; mt++)
#pragma unroll
        for (int r = 0; r < 4; r++) {
            int row = mt * 16 + g * 4 + r;
            float m = fmaxf(fmaxf(red_m[0][row], red_m[1][row]),
                            fmaxf(red_m[2][row], red_m[3][row]));
            float s = 0.f;
#pragma unroll
            for (int nt = 0; nt < 4; nt++) {
                float p = __expf(scale * (acc[mt][nt][r] - m));
                acc[mt][nt][r] = p;
                s += p;
                p_lds[row * CHK + w * 64 + nt * 16 + c] = f2bf(p);
            }
            s += __shfl_xor(s, 1);
            s += __shfl_xor(s, 2);
            s += __shfl_xor(s, 4);
            s += __shfl_xor(s, 8);
            tse[mt][r] = s;
        }
    if (c == 0) {
#pragma unroll
        for (int mt = 0; mt < 3; mt++)
#pragma unroll
            for (int r = 0; r < 4; r++)
                red_se[w][mt * 16 + g * 4 + r] = tse[mt][r];
    }
    __syncthreads();

    if (tid < RPAD) {
        float mm = fmaxf(fmaxf(red_m[0][tid], red_m[1][tid]),
                         fmaxf(red_m[2][tid], red_m[3][tid]));
        float ss = red_se[0][tid] + red_se[1][tid] + red_se[2][tid] + red_se[3][tid];
        m_ws[blk * RPAD + tid]  = mm;
        se_ws[blk * RPAD + tid] = ss;
    }

    f32x4 acc2[3];
#pragma unroll
    for (int mt = 0; mt < 3; mt++) acc2[mt] = (f32x4){0.f, 0.f, 0.f, 0.f};

#pragma unroll
    for (int ks = 0; ks < 8; ks++) {
        int slot = ks * 4 + g;
        int d    = w * 16 + c;
        short8 bf = *reinterpret_cast<const short8*>(
            vt + d * CHK + ((slot ^ (d & 31)) << 3));
#pragma unroll
        for (int mt = 0; mt < 3; mt++) {
            short8 af = *reinterpret_cast<const short8*>(
                p_lds + (mt * 16 + c) * CHK + ks * 32 + g * 8);
            acc2[mt] = __builtin_amdgcn_mfma_f32_16x16x32_bf16(af, bf, acc2[mt], 0, 0, 0);
        }
    }

#pragma unroll
    for (int mt = 0; mt < 3; mt++)
#pragma unroll
        for (int r = 0; r < 4; r++) {
            int row = mt * 16 + g * 4 + r;
            pv_ws[((size_t)blk * RPAD + row) * 64 + w * 16 + c] = acc2[mt][r];
        }
}

// ---------------- Stage 4b: combine chunk partials, write selected rows ----------------
__global__ __launch_bounds__(256) void kernel_attn_comb(const int* __restrict__ top,
                                                        const float* __restrict__ m_ws,
                                                        const float* __restrict__ se_ws,
                                                        const float* __restrict__ pv_ws,
                                                        float* __restrict__ out) {
    int bh = blockIdx.x;
    int b = bh >> 3, h = bh & 7;
    const float scale = 0.125f;
    for (int idx = threadIdx.x; idx < UU * 64; idx += 256) {
        int r = idx >> 6, d = idx & 63;
        float mc[NCHK];
        float mm = -INFINITY;
#pragma unroll
        for (int ch = 0; ch < NCHK; ch++) {
            mc[ch] = m_ws[(bh * NCHK + ch) * RPAD + r];
            mm = fmaxf(mm, mc[ch]);
        }
        float num = 0.f, den = 0.f;
#pragma unroll
        for (int ch = 0; ch < NCHK; ch++) {
            float f = __expf(scale * (mc[ch] - mm));
            num += f * pv_ws[((size_t)(bh * NCHK + ch) * RPAD + r) * 64 + d];
            den += f * se_ws[(bh * NCHK + ch) * RPAD + r];
        }
        out[qkv_off(b, top[bh * UU + r], h, d)] = num / den;
    }
}

extern "C" void kernel_launch(void* const* d_in, const int* in_sizes, int n_in,
                              void* d_out, int out_size, void* d_ws, size_t ws_size,
                              hipStream_t stream) {
    const float* Q    = (const float*)d_in[0];
    const float* K    = (const float*)d_in[1];
    const float* V    = (const float*)d_in[2];
    const int*   sidx = (const int*)d_in[3];
    float* out = (float*)d_out;

    char* ws = (char*)d_ws;
    float* M     = (float*)(ws);                          // 256 KiB
    int*   top   = (int*)  (ws + 262144);                 // 9 KiB
    float* csum  = (float*)(ws + 271360);                 // 512 KiB
    float* m_ws  = (float*)(ws + 795648);                 // 48 KiB
    float* se_ws = (float*)(ws + 844800);                 // 48 KiB
    float* pv_ws = (float*)(ws + 893952);                 // 3 MiB

    kernel_M_csum1   <<<MBLOCKS + C1BLOCKS, 256, 0, stream>>>(Q, K, V, sidx, M, csum);
    kernel_topk_csum2<<<BH + C1BLOCKS, 64, 0, stream>>>(M, top, V, csum, out);
    kernel_attn_part <<<BH * NCHK, 256, 0, stream>>>(Q, K, V, top, m_ws, se_ws, pv_ws);
    kernel_attn_comb <<<BH, 256, 0, stream>>>(top, m_ws, se_ws, pv_ws, out);
}

// Round 8
// 78.383 us; speedup vs baseline: 1.7595x; 1.7595x over previous
//
#include <hip/hip_runtime.h>
#include <math.h>

#define BB 8
#define LL 1024
#define HH 8
#define DD 64
#define SS 35
#define UU 35
#define BH (BB*HH)
#define CH 32            // cumsum chunks per (b,h)
#define CROWS (LL/CH)    // 32 rows per chunk
#define NCHK 4           // attention K/V chunks
#define CHK 256          // keys per chunk
#define RPAD 48          // padded row count (35 -> 48, 3 m-tiles)

#define MBLOCKS (BB*LL)  // stage-1: one block per (b,q); b=blk&7 pins XCD
#define C1BLOCKS (BH*CH) // 2048

typedef __attribute__((ext_vector_type(8))) short short8;
typedef __attribute__((ext_vector_type(4))) float f32x4;

__device__ __forceinline__ size_t qkv_off(int b, int l, int h, int d) {
    return (((size_t)b*LL + l)*HH + h)*DD + d;
}

__device__ __forceinline__ unsigned short f2bf(float x) {
    unsigned int u = __float_as_uint(x);
    u = (u + 0x7fffu + ((u >> 16) & 1u)) >> 16;
    return (unsigned short)u;
}

__device__ __forceinline__ short8 ld_bf8_g(const float* __restrict__ p) {
    float4 x = *reinterpret_cast<const float4*>(p);
    float4 y = *reinterpret_cast<const float4*>(p + 4);
    short8 r;
    r[0] = (short)f2bf(x.x); r[1] = (short)f2bf(x.y);
    r[2] = (short)f2bf(x.z); r[3] = (short)f2bf(x.w);
    r[4] = (short)f2bf(y.x); r[5] = (short)f2bf(y.y);
    r[6] = (short)f2bf(y.z); r[7] = (short)f2bf(y.w);
    return r;
}

// ---------------- L1: kernel_M (block per (b,q), all 8 h per gather) + csum1 ----------------
__global__ __launch_bounds__(256, 4) void kernel_M_csum1(const float* __restrict__ Q,
                                                         const float* __restrict__ K,
                                                         const float* __restrict__ V,
                                                         const int*   __restrict__ sidx,
                                                         float* __restrict__ M,
                                                         float* __restrict__ csum) {
    int blk = blockIdx.x;
    if (blk < MBLOCKS) {
        // ---- M: one block per (b,q); gather K[b,idx,:,:] (2KB, all 8 heads) ----
        __shared__ float s_mx[4][8];
        __shared__ float s_sm[4][8];
        int b = blk & 7;                 // = XCD id under %8 round-robin dispatch
        int q = blk >> 3;
        int tid = threadIdx.x;
        int w = tid >> 6, lane = tid & 63;
        int h = lane >> 3, dsub = (lane & 7) * 4;   // lane owns d[dsub..+4) and d[dsub+32..+4)

        // Q row-slice in regs (covers all 8 heads across the wave)
        const float* qb = Q + ((size_t)(b * LL + q) * HH) * DD + h * DD + dsub;
        f32x4 q0 = *reinterpret_cast<const f32x4*>(qb);
        f32x4 q1 = *reinterpret_cast<const f32x4*>(qb + 32);

        // wave w owns samples s = w + 4*i (9 slots; w=3,i=8 invalid -> dup, masked)
        const int* sq = sidx + q * SS;
        int sl[9];
#pragma unroll
        for (int i = 0; i < 9; i++) {
            int s = w + 4 * i;
            sl[i] = sq[s < SS ? s : w];   // wave-uniform -> scalar loads
        }

        const float* kbase = K + (size_t)b * (LL * HH * DD) + h * DD + dsub;
        float dots[9];
#pragma unroll
        for (int g = 0; g < 3; g++) {
            f32x4 ka[3], kc[3];
#pragma unroll
            for (int j = 0; j < 3; j++) {
                const float* kp = kbase + (size_t)sl[g * 3 + j] * (HH * DD);
                ka[j] = *reinterpret_cast<const f32x4*>(kp);
                kc[j] = *reinterpret_cast<const f32x4*>(kp + 32);
            }
#pragma unroll
            for (int j = 0; j < 3; j++) {
                float d = q0.x * ka[j].x + q0.y * ka[j].y + q0.z * ka[j].z + q0.w * ka[j].w
                        + q1.x * kc[j].x + q1.y * kc[j].y + q1.z * kc[j].z + q1.w * kc[j].w;
                d += __shfl_xor(d, 1);
                d += __shfl_xor(d, 2);
                d += __shfl_xor(d, 4);    // all 8 lanes of h-group now hold full dot
                dots[g * 3 + j] = d;
            }
        }

        float mx = -INFINITY, sm = 0.f;
#pragma unroll
        for (int i = 0; i < 9; i++) {
            if (w + 4 * i < SS) { mx = fmaxf(mx, dots[i]); sm += dots[i]; }
        }
        if ((lane & 7) == 0) { s_mx[w][h] = mx; s_sm[w][h] = sm; }
        __syncthreads();
        if (tid < 8) {
            float m2 = fmaxf(fmaxf(s_mx[0][tid], s_mx[1][tid]),
                             fmaxf(s_mx[2][tid], s_mx[3][tid]));
            float s2 = s_sm[0][tid] + s_sm[1][tid] + s_sm[2][tid] + s_sm[3][tid];
            M[(b * HH + tid) * LL + q] = m2 - s2 * (1.0f / LL);
        }
    } else {
        // ---- csum1: per-chunk column sums ----
        int blk2 = blk - MBLOCKS;
        int bh = blk2 >> 5, c = blk2 & (CH - 1);
        int b = bh >> 3, h = bh & 7;
        int d = threadIdx.x & 63, seg = threadIdx.x >> 6;
        int l0 = c * CROWS + seg * (CROWS / 4);
        const float* vp = V + qkv_off(b, l0, h, d);
        float vr[CROWS / 4];
#pragma unroll
        for (int i = 0; i < CROWS / 4; i++) vr[i] = vp[(size_t)i * (HH * DD)];
        float s = 0.f;
#pragma unroll
        for (int i = 0; i < CROWS / 4; i++) s += vr[i];
        __shared__ float red[4][64];
        red[seg][d] = s;
        __syncthreads();
        if (seg == 0)
            csum[(size_t)blk2 * 64 + d] = red[0][d] + red[1][d] + red[2][d] + red[3][d];
    }
}

// ---------------- L2: topk + csum2 fused (64-thread blocks) ----------------
__global__ __launch_bounds__(64, 4) void kernel_topk_csum2(const float* __restrict__ M,
                                                           int* __restrict__ top,
                                                           const float* __restrict__ V,
                                                           const float* __restrict__ csum,
                                                           float* __restrict__ out) {
    if (blockIdx.x < BH) {
        // ---- top-U per (b,h), single wave, shfl-only ----
        int bh = blockIdx.x, lane = threadIdx.x;
        float v[16];
#pragma unroll
        for (int i = 0; i < 16; i++) v[i] = M[bh * LL + i * 64 + lane];

        for (int k = 0; k < UU; k++) {
            float bv = -INFINITY; int bi = 0x7fffffff;
#pragma unroll
            for (int i = 0; i < 16; i++) {
                if (v[i] > bv) { bv = v[i]; bi = i * 64 + lane; }
            }
#pragma unroll
            for (int w = 1; w < 64; w <<= 1) {
                float ov = __shfl_xor(bv, w);
                int   oi = __shfl_xor(bi, w);
                if (ov > bv || (ov == bv && oi < bi)) { bv = ov; bi = oi; }
            }
            if (lane == 0) top[bh * UU + k] = bi;
            if ((bi & 63) == lane) {
                int slot = bi >> 6;
#pragma unroll
                for (int i = 0; i < 16; i++) if (i == slot) v[i] = -INFINITY;
            }
        }
    } else {
        // ---- csum2: scan within chunk, write context ----
        int blk = blockIdx.x - BH;
        int bh = blk >> 5, c = blk & (CH - 1);
        int b = bh >> 3, h = bh & 7;
        int d = threadIdx.x;
        int l0 = c * CROWS;
        const float* vp = V + qkv_off(b, l0, h, d);

        float vr[CROWS];
#pragma unroll
        for (int i = 0; i < CROWS; i++) vr[i] = vp[(size_t)i * (HH * DD)];

        float prefix = 0.f;
#pragma unroll
        for (int cc = 0; cc < CH; cc++) {
            float vv = csum[(size_t)(bh * CH + cc) * 64 + d];
            prefix += (cc < c) ? vv : 0.f;
        }
        float* op = out + qkv_off(b, l0, h, d);
        float run = prefix;
#pragma unroll
        for (int i = 0; i < CROWS; i++) {
            run += vr[i];
            op[(size_t)i * (HH * DD)] = run / (float)(l0 + i + 1);
        }
    }
}

// ---------------- Stage 4a: MFMA flash-attention partials per (bh, chunk) ----------------
__global__ __launch_bounds__(256) void kernel_attn_part(const float* __restrict__ Q,
                                                        const float* __restrict__ K,
                                                        const float* __restrict__ V,
                                                        const int*   __restrict__ top,
                                                        float* __restrict__ m_ws,
                                                        float* __restrict__ se_ws,
                                                        float* __restrict__ pv_ws) {
    __shared__ unsigned short vt[64 * CHK];      // V^T, 16B-slot swizzled
    __shared__ unsigned short p_lds[RPAD * CHK]; // P (exp'd scores), bf16
    __shared__ float red_m[4][RPAD];
    __shared__ float red_se[4][RPAD];
    __shared__ int   qpos_s[RPAD];

    const int blk = blockIdx.x;          // bh*NCHK + ch
    const int bh  = blk >> 2;
    const int ch  = blk & 3;
    const int b   = bh >> 3, h = bh & 7;
    const int l0  = ch * CHK;
    const int tid = threadIdx.x;
    const int w    = tid >> 6;
    const int lane = tid & 63;
    const int c    = lane & 15;
    const int g    = lane >> 4;
    const float scale = 0.125f;

    if (tid < RPAD) qpos_s[tid] = top[bh * UU + (tid < UU ? tid : UU - 1)];

#pragma unroll
    for (int i = 0; i < 8; i++) {
        int task = i * 256 + tid;
        int d   = task & 63;
        int lq8 = task >> 6;
        float vv[8];
#pragma unroll
        for (int j = 0; j < 8; j++)
            vv[j] = V[qkv_off(b, l0 + lq8 * 8 + j, h, d)];
        short8 pk;
#pragma unroll
        for (int j = 0; j < 8; j++) pk[j] = (short)f2bf(vv[j]);
        *reinterpret_cast<short8*>(vt + d * CHK + (((lq8 ^ (d & 31)) << 3))) = pk;
    }
    __syncthreads();

    f32x4 acc[3][4];
#pragma unroll
    for (int mt = 0; mt < 3; mt++)
#pragma unroll
        for (int nt = 0; nt < 4; nt++) acc[mt][nt] = (f32x4){0.f, 0.f, 0.f, 0.f};

#pragma unroll
    for (int ks = 0; ks < 2; ks++) {
        int k0 = ks * 32 + g * 8;
        short8 af[3];
#pragma unroll
        for (int mt = 0; mt < 3; mt++) {
            int row = mt * 16 + c;
            af[mt] = ld_bf8_g(Q + qkv_off(b, qpos_s[row], h, k0));
        }
#pragma unroll
        for (int nt = 0; nt < 4; nt++) {
            int kl = l0 + w * 64 + nt * 16 + c;
            short8 bf = ld_bf8_g(K + qkv_off(b, kl, h, k0));
#pragma unroll
            for (int mt = 0; mt < 3; mt++)
                acc[mt][nt] = __builtin_amdgcn_mfma_f32_16x16x32_bf16(af[mt], bf, acc[mt][nt], 0, 0, 0);
        }
    }

    float tmax[3][4];
#pragma unroll
    for (int mt = 0; mt < 3; mt++)
#pragma unroll
        for (int r = 0; r < 4; r++) {
            float m = fmaxf(fmaxf(acc[mt][0][r], acc[mt][1][r]),
                            fmaxf(acc[mt][2][r], acc[mt][3][r]));
            m = fmaxf(m, __shfl_xor(m, 1));
            m = fmaxf(m, __shfl_xor(m, 2));
            m = fmaxf(m, __shfl_xor(m, 4));
            m = fmaxf(m, __shfl_xor(m, 8));
            tmax[mt][r] = m;
        }
    if (c == 0) {
#pragma unroll
        for (int mt = 0; mt < 3; mt++)
#pragma unroll
            for (int r = 0; r < 4; r++)
                red_m[w][mt * 16 + g * 4 + r] = tmax[mt][r];
    }
    __syncthreads();

    float tse[3][4];
#pragma unroll
    for (int mt = 0; mt < 3; mt++)
#pragma unroll
        for (int r = 0; r < 4; r++) {
            int row = mt * 16 + g * 4 + r;
            float m = fmaxf(fmaxf(red_m[0][row], red_m[1][row]),
                            fmaxf(red_m[2][row], red_m[3][row]));
            float s = 0.f;
#pragma unroll
            for (int nt = 0; nt < 4; nt++) {
                float p = __expf(scale * (acc[mt][nt][r] - m));
                acc[mt][nt][r] = p;
                s += p;
                p_lds[row * CHK + w * 64 + nt * 16 + c] = f2bf(p);
            }
            s += __shfl_xor(s, 1);
            s += __shfl_xor(s, 2);
            s += __shfl_xor(s, 4);
            s += __shfl_xor(s, 8);
            tse[mt][r] = s;
        }
    if (c == 0) {
#pragma unroll
        for (int mt = 0; mt < 3; mt++)
#pragma unroll
            for (int r = 0; r < 4; r++)
                red_se[w][mt * 16 + g * 4 + r] = tse[mt][r];
    }
    __syncthreads();

    if (tid < RPAD) {
        float mm = fmaxf(fmaxf(red_m[0][tid], red_m[1][tid]),
                         fmaxf(red_m[2][tid], red_m[3][tid]));
        float ss = red_se[0][tid] + red_se[1][tid] + red_se[2][tid] + red_se[3][tid];
        m_ws[blk * RPAD + tid]  = mm;
        se_ws[blk * RPAD + tid] = ss;
    }

    f32x4 acc2[3];
#pragma unroll
    for (int mt = 0; mt < 3; mt++) acc2[mt] = (f32x4){0.f, 0.f, 0.f, 0.f};

#pragma unroll
    for (int ks = 0; ks < 8; ks++) {
        int slot = ks * 4 + g;
        int d    = w * 16 + c;
        short8 bf = *reinterpret_cast<const short8*>(
            vt + d * CHK + ((slot ^ (d & 31)) << 3));
#pragma unroll
        for (int mt = 0; mt < 3; mt++) {
            short8 af = *reinterpret_cast<const short8*>(
                p_lds + (mt * 16 + c) * CHK + ks * 32 + g * 8);
            acc2[mt] = __builtin_amdgcn_mfma_f32_16x16x32_bf16(af, bf, acc2[mt], 0, 0, 0);
        }
    }

#pragma unroll
    for (int mt = 0; mt < 3; mt++)
#pragma unroll
        for (int r = 0; r < 4; r++) {
            int row = mt * 16 + g * 4 + r;
            pv_ws[((size_t)blk * RPAD + row) * 64 + w * 16 + c] = acc2[mt][r];
        }
}

// ---------------- Stage 4b: combine chunk partials, write selected rows ----------------
__global__ __launch_bounds__(256) void kernel_attn_comb(const int* __restrict__ top,
                                                        const float* __restrict__ m_ws,
                                                        const float* __restrict__ se_ws,
                                                        const float* __restrict__ pv_ws,
                                                        float* __restrict__ out) {
    int bh = blockIdx.x;
    int b = bh >> 3, h = bh & 7;
    const float scale = 0.125f;
    for (int idx = threadIdx.x; idx < UU * 64; idx += 256) {
        int r = idx >> 6, d = idx & 63;
        float mc[NCHK];
        float mm = -INFINITY;
#pragma unroll
        for (int ch = 0; ch < NCHK; ch++) {
            mc[ch] = m_ws[(bh * NCHK + ch) * RPAD + r];
            mm = fmaxf(mm, mc[ch]);
        }
        float num = 0.f, den = 0.f;
#pragma unroll
        for (int ch = 0; ch < NCHK; ch++) {
            float f = __expf(scale * (mc[ch] - mm));
            num += f * pv_ws[((size_t)(bh * NCHK + ch) * RPAD + r) * 64 + d];
            den += f * se_ws[(bh * NCHK + ch) * RPAD + r];
        }
        out[qkv_off(b, top[bh * UU + r], h, d)] = num / den;
    }
}

extern "C" void kernel_launch(void* const* d_in, const int* in_sizes, int n_in,
                              void* d_out, int out_size, void* d_ws, size_t ws_size,
                              hipStream_t stream) {
    const float* Q    = (const float*)d_in[0];
    const float* K    = (const float*)d_in[1];
    const float* V    = (const float*)d_in[2];
    const int*   sidx = (const int*)d_in[3];
    float* out = (float*)d_out;

    char* ws = (char*)d_ws;
    float* M     = (float*)(ws);                          // 256 KiB
    int*   top   = (int*)  (ws + 262144);                 // 9 KiB
    float* csum  = (float*)(ws + 271360);                 // 512 KiB
    float* m_ws  = (float*)(ws + 795648);                 // 48 KiB
    float* se_ws = (float*)(ws + 844800);                 // 48 KiB
    float* pv_ws = (float*)(ws + 893952);                 // 3 MiB

    kernel_M_csum1   <<<MBLOCKS + C1BLOCKS, 256, 0, stream>>>(Q, K, V, sidx, M, csum);
    kernel_topk_csum2<<<BH + C1BLOCKS, 64, 0, stream>>>(M, top, V, csum, out);
    kernel_attn_part <<<BH * NCHK, 256, 0, stream>>>(Q, K, V, top, m_ws, se_ws, pv_ws);
    kernel_attn_comb <<<BH, 256, 0, stream>>>(top, m_ws, se_ws, pv_ws, out);
}